// Round 10
// baseline (97.585 us; speedup 1.0000x reference)
//
#include <hip/hip_runtime.h>

#define N_NODES 100000
#define B_TOTAL 50000
#define NSAMP   16
#define FDIM    256
#define KDIM    512   // 2*FDIM
#define EDIM    256
#define NBT     64    // batch columns per GEMM block
#define B_PAD   50048 // B_TOTAL rounded to NBT
#define NBLK    (B_PAD / NBT)   // 782

// ws layout (full path):
//   X image [blk][kc=4][rloc=64][256B swizzled] -> 64KB/blk
#define XCHUNK   16384
#define XBLK     (4 * XCHUNK)
#define XIMG_SZ  ((size_t)NBLK * XBLK)          // 51.2MB
#define WIMG_OFF XIMG_SZ
#define WIMG_SZ  ((size_t)4 * 65536)            // 256KB
#define F8_OFF   (WIMG_OFF + WIMG_SZ)
#define F8_SZ    ((size_t)N_NODES * FDIM)       // 25.6MB
#define FB_OFF   (F8_OFF + F8_SZ)
#define FB_SZ    ((size_t)N_NODES * FDIM * 2)   // 51.2MB
#define WS_FULL  (FB_OFF + FB_SZ)               // ~128.3MB
#define WS_F8    (F8_OFF + F8_SZ)               // ~77.1MB (r9 path)

#define FP_BLOCKS 12500   // N_NODES*FDIM/8/256
#define PW_BLOCKS 128

typedef __attribute__((ext_vector_type(4))) float float4v;
typedef __attribute__((ext_vector_type(2))) float float2v;
typedef __attribute__((ext_vector_type(4))) short short4v;
typedef __attribute__((ext_vector_type(8))) short short8v;
typedef __attribute__((ext_vector_type(2))) unsigned int uint2v;

__device__ __forceinline__ unsigned short f2bf(float f) {
  unsigned int u = __builtin_bit_cast(unsigned int, f);
  u += 0x7FFFu + ((u >> 16) & 1u);   // round-to-nearest-even
  return (unsigned short)(u >> 16);
}

__device__ __forceinline__ short4v pack4(float4v v) {
  short4v r;
  r[0] = (short)f2bf(v[0]);
  r[1] = (short)f2bf(v[1]);
  r[2] = (short)f2bf(v[2]);
  r[3] = (short)f2bf(v[3]);
  return r;
}

// ---------------- fp8 e4m3fn encode/decode (hw builtin if available) -------
#if defined(__has_builtin)
#if __has_builtin(__builtin_amdgcn_cvt_pk_f32_fp8) && __has_builtin(__builtin_amdgcn_cvt_pk_fp8_f32)
#define HAS_HW_FP8 1
#endif
#endif

#ifdef HAS_HW_FP8
__device__ __forceinline__ float2v f8_lo(unsigned int d) {
  return (float2v)__builtin_amdgcn_cvt_pk_f32_fp8((int)d, false);
}
__device__ __forceinline__ float2v f8_hi(unsigned int d) {
  return (float2v)__builtin_amdgcn_cvt_pk_f32_fp8((int)d, true);
}
__device__ __forceinline__ uint2v f8_enc8(float4v a, float4v b) {
  int w0 = __builtin_amdgcn_cvt_pk_fp8_f32(a[0], a[1], 0, false);
  w0 = __builtin_amdgcn_cvt_pk_fp8_f32(a[2], a[3], w0, true);
  int w1 = __builtin_amdgcn_cvt_pk_fp8_f32(b[0], b[1], 0, false);
  w1 = __builtin_amdgcn_cvt_pk_fp8_f32(b[2], b[3], w1, true);
  uint2v r; r[0] = (unsigned)w0; r[1] = (unsigned)w1;
  return r;
}
#else
__device__ __forceinline__ float f8_dec1(unsigned int b) {
  unsigned int s = b >> 7, e = (b >> 3) & 15, m = b & 7;
  float fn = __builtin_bit_cast(float, (s << 31) | ((e + 120) << 23) | (m << 20));
  float fs = (float)(int)m * 0.001953125f;       // m * 2^-9
  fs = s ? -fs : fs;
  return e ? fn : fs;
}
__device__ __forceinline__ float2v f8_lo(unsigned int d) {
  float2v r; r[0] = f8_dec1(d & 255u); r[1] = f8_dec1((d >> 8) & 255u); return r;
}
__device__ __forceinline__ float2v f8_hi(unsigned int d) {
  float2v r; r[0] = f8_dec1((d >> 16) & 255u); r[1] = f8_dec1(d >> 24); return r;
}
__device__ __forceinline__ unsigned int f8_enc1(float x) {
  unsigned int u = __builtin_bit_cast(unsigned int, x);
  unsigned int s = (u >> 31) << 7;
  float ax = __builtin_fabsf(x);
  if (ax < 0.015625f) {
    unsigned int m = (unsigned int)__builtin_rintf(ax * 512.0f);
    return s | m;
  }
  if (ax > 448.0f) return s | 0x7E;
  unsigned int au = u & 0x7fffffffu;
  unsigned int t = au + 0x7FFFFu + ((au >> 20) & 1u);
  unsigned int E = t >> 23;
  return s | (((E - 120u) & 0xFu) << 3) | ((t >> 20) & 7u);
}
__device__ __forceinline__ uint2v f8_enc8(float4v a, float4v b) {
  uint2v r;
  r[0] = f8_enc1(a[0]) | (f8_enc1(a[1]) << 8) | (f8_enc1(a[2]) << 16) | (f8_enc1(a[3]) << 24);
  r[1] = f8_enc1(b[0]) | (f8_enc1(b[1]) << 8) | (f8_enc1(b[2]) << 16) | (f8_enc1(b[3]) << 24);
  return r;
}
#endif

// Inline-asm loads: compiler cannot serialize these; we wait manually.
__device__ __forceinline__ unsigned int ld4(const void* p) {
  unsigned int r;
  asm volatile("global_load_dword %0, %1, off" : "=v"(r) : "v"(p) : "memory");
  return r;
}
__device__ __forceinline__ uint2v ld8(const void* p) {
  uint2v r;
  asm volatile("global_load_dwordx2 %0, %1, off" : "=v"(r) : "v"(p) : "memory");
  return r;
}
__device__ __forceinline__ float4v ld16f(const void* p) {
  float4v r;
  asm volatile("global_load_dwordx4 %0, %1, off" : "=v"(r) : "v"(p) : "memory");
  return r;
}

__device__ __forceinline__ void lds_load16(const void* g, void* l) {
  __builtin_amdgcn_global_load_lds(
      (const __attribute__((address_space(1))) unsigned int*)g,
      (__attribute__((address_space(3))) unsigned int*)l, 16, 0, 0);
}

// ---------------------------------------------------------------------------
// Kernel A (full path): one launch writes fp8 table + bf16 table + W image.
// 102MB f32 read, 25.6+51.2+0.25MB writes, all streaming.
// ---------------------------------------------------------------------------
__global__ __launch_bounds__(256) void prep_pack(
    const float* __restrict__ f,
    unsigned char* __restrict__ o8,
    unsigned short* __restrict__ ob,
    const float* __restrict__ weight,
    unsigned char* __restrict__ wimg) {
  if (blockIdx.x < FP_BLOCKS) {
    const size_t i = ((size_t)blockIdx.x * 256 + threadIdx.x) * 8;
    float4v a = *(const float4v*)(f + i);
    float4v b = *(const float4v*)(f + i + 4);
    *(uint2v*)(o8 + i) = f8_enc8(a, b);
    short4v ra = pack4(a), rb = pack4(b);
    short8v r;
    r[0]=ra[0]; r[1]=ra[1]; r[2]=ra[2]; r[3]=ra[3];
    r[4]=rb[0]; r[5]=rb[1]; r[6]=rb[2]; r[7]=rb[3];
    *(short8v*)(ob + i) = r;
  } else {
    const int idx = (blockIdx.x - FP_BLOCKS) * 256 + threadIdx.x;  // 32768
    const int e  = idx >> 7;
    const int kq = idx & 127;
    const int k  = kq * 4;
    const int kc = k >> 7;
    const int kl = k & 127;
    float4v wv = *(const float4v*)(weight + (size_t)e * KDIM + k);
    *(short4v*)(wimg + kc * 65536 + e * 256 +
                (((unsigned)(kl * 2)) ^ ((unsigned)(e & 7) << 4))) = pack4(wv);
  }
}

// ---------------------------------------------------------------------------
// Kernel 1 (full path): gather + mean. Self from bf16 table (8B/lane, stored
// straight through); neighbors from fp8 table (4B/lane, error damped 4x by
// the 1/16 mean). One wave per row, 17 asm loads in flight, single vmcnt(0).
// Demand: 205MB fp8 + 25.6MB bf16 self.
// ---------------------------------------------------------------------------
__global__ __launch_bounds__(256, 4) void gather_mean_f8b(
    const int* __restrict__ nodes,
    const int* __restrict__ neigh,
    const unsigned short* __restrict__ fb,
    const unsigned char* __restrict__ f8,
    unsigned char* __restrict__ ximg) {
  const int l = threadIdx.x & 63;
  const int w = threadIdx.x >> 6;
  const int row = __builtin_amdgcn_readfirstlane(blockIdx.x * 4 + w);
  if (row >= B_PAD) return;

  const int blk  = row >> 6;
  const int rloc = row & 63;
  unsigned char* base = ximg + (size_t)blk * XBLK + rloc * 256;
  const unsigned int sw  = (unsigned)(rloc & 7) << 4;
  const unsigned int off = (((unsigned)(l * 8)) & 255u) ^ sw;
  const int kcs = l >> 5;

  if (row < B_TOTAL) {
    const int node = nodes[row];
    const int* ni = neigh + row * NSAMP;
    uint2v vs = ld8(fb + (size_t)node * FDIM + (size_t)l * 4);   // 4 bf16 self
    const size_t fo = (size_t)l * 4;                             // 4B fp8/lane
    unsigned int d0  = ld4(f8 + (size_t)ni[ 0] * FDIM + fo);
    unsigned int d1  = ld4(f8 + (size_t)ni[ 1] * FDIM + fo);
    unsigned int d2  = ld4(f8 + (size_t)ni[ 2] * FDIM + fo);
    unsigned int d3  = ld4(f8 + (size_t)ni[ 3] * FDIM + fo);
    unsigned int d4  = ld4(f8 + (size_t)ni[ 4] * FDIM + fo);
    unsigned int d5  = ld4(f8 + (size_t)ni[ 5] * FDIM + fo);
    unsigned int d6  = ld4(f8 + (size_t)ni[ 6] * FDIM + fo);
    unsigned int d7  = ld4(f8 + (size_t)ni[ 7] * FDIM + fo);
    unsigned int d8  = ld4(f8 + (size_t)ni[ 8] * FDIM + fo);
    unsigned int d9  = ld4(f8 + (size_t)ni[ 9] * FDIM + fo);
    unsigned int d10 = ld4(f8 + (size_t)ni[10] * FDIM + fo);
    unsigned int d11 = ld4(f8 + (size_t)ni[11] * FDIM + fo);
    unsigned int d12 = ld4(f8 + (size_t)ni[12] * FDIM + fo);
    unsigned int d13 = ld4(f8 + (size_t)ni[13] * FDIM + fo);
    unsigned int d14 = ld4(f8 + (size_t)ni[14] * FDIM + fo);
    unsigned int d15 = ld4(f8 + (size_t)ni[15] * FDIM + fo);
    asm volatile("s_waitcnt vmcnt(0)" ::: "memory");
    __builtin_amdgcn_sched_barrier(0);

    float2v lo0 = f8_lo(d0)  + f8_lo(d1);
    float2v lo1 = f8_lo(d2)  + f8_lo(d3);
    float2v lo2 = f8_lo(d4)  + f8_lo(d5);
    float2v lo3 = f8_lo(d6)  + f8_lo(d7);
    float2v lo4 = f8_lo(d8)  + f8_lo(d9);
    float2v lo5 = f8_lo(d10) + f8_lo(d11);
    float2v lo6 = f8_lo(d12) + f8_lo(d13);
    float2v lo7 = f8_lo(d14) + f8_lo(d15);
    lo0 += lo1; lo2 += lo3; lo4 += lo5; lo6 += lo7;
    lo0 += lo2; lo4 += lo6;
    lo0 += lo4;
    float2v hi0 = f8_hi(d0)  + f8_hi(d1);
    float2v hi1 = f8_hi(d2)  + f8_hi(d3);
    float2v hi2 = f8_hi(d4)  + f8_hi(d5);
    float2v hi3 = f8_hi(d6)  + f8_hi(d7);
    float2v hi4 = f8_hi(d8)  + f8_hi(d9);
    float2v hi5 = f8_hi(d10) + f8_hi(d11);
    float2v hi6 = f8_hi(d12) + f8_hi(d13);
    float2v hi7 = f8_hi(d14) + f8_hi(d15);
    hi0 += hi1; hi2 += hi3; hi4 += hi5; hi6 += hi7;
    hi0 += hi2; hi4 += hi6;
    hi0 += hi4;

    float4v a0;
    a0[0] = lo0[0] * 0.0625f;
    a0[1] = lo0[1] * 0.0625f;
    a0[2] = hi0[0] * 0.0625f;
    a0[3] = hi0[1] * 0.0625f;

    *(uint2v*)(base + kcs * XCHUNK + off)        = vs;          // self bf16
    *(short4v*)(base + (2 + kcs) * XCHUNK + off) = pack4(a0);   // mean
  } else {
    uint2v z = {0u, 0u};
    *(uint2v*)(base + kcs * XCHUNK + off)       = z;
    *(uint2v*)(base + (2 + kcs) * XCHUNK + off) = z;
  }
}

// ---------------------------------------------------------------------------
// Kernel A' / 0' / 1' (reduced-ws path, r9-proven): fp8-only pipeline.
// ---------------------------------------------------------------------------
__global__ __launch_bounds__(256) void fp8_pack(
    const float* __restrict__ f, unsigned char* __restrict__ o) {
  const size_t i = ((size_t)blockIdx.x * 256 + threadIdx.x) * 8;
  if (i >= (size_t)N_NODES * FDIM) return;
  float4v a = *(const float4v*)(f + i);
  float4v b = *(const float4v*)(f + i + 4);
  *(uint2v*)(o + i) = f8_enc8(a, b);
}

__global__ __launch_bounds__(256) void pack_w(
    const float* __restrict__ weight, unsigned char* __restrict__ wimg) {
  const int idx = blockIdx.x * 256 + threadIdx.x;
  const int e  = idx >> 7;
  const int kq = idx & 127;
  const int k  = kq * 4;
  const int kc = k >> 7;
  const int kl = k & 127;
  float4v wv = *(const float4v*)(weight + (size_t)e * KDIM + k);
  *(short4v*)(wimg + kc * 65536 + e * 256 +
              (((unsigned)(kl * 2)) ^ ((unsigned)(e & 7) << 4))) = pack4(wv);
}

__global__ __launch_bounds__(256, 4) void gather_mean_f8(
    const int* __restrict__ nodes,
    const int* __restrict__ neigh,
    const float* __restrict__ features,
    const unsigned char* __restrict__ f8,
    unsigned char* __restrict__ ximg) {
  const int l = threadIdx.x & 63;
  const int w = threadIdx.x >> 6;
  const int row = __builtin_amdgcn_readfirstlane(blockIdx.x * 4 + w);
  if (row >= B_PAD) return;

  const int blk  = row >> 6;
  const int rloc = row & 63;
  unsigned char* base = ximg + (size_t)blk * XBLK + rloc * 256;
  const unsigned int sw  = (unsigned)(rloc & 7) << 4;
  const unsigned int off = (((unsigned)(l * 8)) & 255u) ^ sw;
  const int kcs = l >> 5;

  if (row < B_TOTAL) {
    const int node = nodes[row];
    const int* ni = neigh + row * NSAMP;
    float4v vs = ld16f(features + (size_t)node * FDIM + l * 4);
    const size_t fo = (size_t)l * 4;
    unsigned int d0  = ld4(f8 + (size_t)ni[ 0] * FDIM + fo);
    unsigned int d1  = ld4(f8 + (size_t)ni[ 1] * FDIM + fo);
    unsigned int d2  = ld4(f8 + (size_t)ni[ 2] * FDIM + fo);
    unsigned int d3  = ld4(f8 + (size_t)ni[ 3] * FDIM + fo);
    unsigned int d4  = ld4(f8 + (size_t)ni[ 4] * FDIM + fo);
    unsigned int d5  = ld4(f8 + (size_t)ni[ 5] * FDIM + fo);
    unsigned int d6  = ld4(f8 + (size_t)ni[ 6] * FDIM + fo);
    unsigned int d7  = ld4(f8 + (size_t)ni[ 7] * FDIM + fo);
    unsigned int d8  = ld4(f8 + (size_t)ni[ 8] * FDIM + fo);
    unsigned int d9  = ld4(f8 + (size_t)ni[ 9] * FDIM + fo);
    unsigned int d10 = ld4(f8 + (size_t)ni[10] * FDIM + fo);
    unsigned int d11 = ld4(f8 + (size_t)ni[11] * FDIM + fo);
    unsigned int d12 = ld4(f8 + (size_t)ni[12] * FDIM + fo);
    unsigned int d13 = ld4(f8 + (size_t)ni[13] * FDIM + fo);
    unsigned int d14 = ld4(f8 + (size_t)ni[14] * FDIM + fo);
    unsigned int d15 = ld4(f8 + (size_t)ni[15] * FDIM + fo);
    asm volatile("s_waitcnt vmcnt(0)" ::: "memory");
    __builtin_amdgcn_sched_barrier(0);

    float2v lo0 = f8_lo(d0)  + f8_lo(d1);
    float2v lo1 = f8_lo(d2)  + f8_lo(d3);
    float2v lo2 = f8_lo(d4)  + f8_lo(d5);
    float2v lo3 = f8_lo(d6)  + f8_lo(d7);
    float2v lo4 = f8_lo(d8)  + f8_lo(d9);
    float2v lo5 = f8_lo(d10) + f8_lo(d11);
    float2v lo6 = f8_lo(d12) + f8_lo(d13);
    float2v lo7 = f8_lo(d14) + f8_lo(d15);
    lo0 += lo1; lo2 += lo3; lo4 += lo5; lo6 += lo7;
    lo0 += lo2; lo4 += lo6;
    lo0 += lo4;
    float2v hi0 = f8_hi(d0)  + f8_hi(d1);
    float2v hi1 = f8_hi(d2)  + f8_hi(d3);
    float2v hi2 = f8_hi(d4)  + f8_hi(d5);
    float2v hi3 = f8_hi(d6)  + f8_hi(d7);
    float2v hi4 = f8_hi(d8)  + f8_hi(d9);
    float2v hi5 = f8_hi(d10) + f8_hi(d11);
    float2v hi6 = f8_hi(d12) + f8_hi(d13);
    float2v hi7 = f8_hi(d14) + f8_hi(d15);
    hi0 += hi1; hi2 += hi3; hi4 += hi5; hi6 += hi7;
    hi0 += hi2; hi4 += hi6;
    hi0 += hi4;

    float4v a0;
    a0[0] = lo0[0] * 0.0625f;
    a0[1] = lo0[1] * 0.0625f;
    a0[2] = hi0[0] * 0.0625f;
    a0[3] = hi0[1] * 0.0625f;

    *(short4v*)(base + kcs * XCHUNK + off)       = pack4(vs);
    *(short4v*)(base + (2 + kcs) * XCHUNK + off) = pack4(a0);
  } else {
    short4v z = {0, 0, 0, 0};
    *(short4v*)(base + kcs * XCHUNK + off)       = z;
    *(short4v*)(base + (2 + kcs) * XCHUNK + off) = z;
  }
}

// ---------------------------------------------------------------------------
// Kernel 2: out[e,b] = relu( sum_k W[e,k] * X[b,k] ), MFMA bf16.
// ---------------------------------------------------------------------------
__global__ __launch_bounds__(256) void gemm_relu(
    const unsigned char* __restrict__ ximg,
    const unsigned char* __restrict__ wimg,
    float* __restrict__ out) {
  __shared__ alignas(16) unsigned char lds_w[EDIM * 256];   // 64KB
  __shared__ alignas(16) unsigned char lds_x[NBT * 256];    // 16KB

  const int tid = threadIdx.x;
  const int l   = tid & 63;
  const int w   = tid >> 6;
  const int lr  = l & 15;
  const int g   = l >> 4;
  const int b0  = blockIdx.x * NBT;
  const unsigned char* xsrc = ximg + (size_t)blockIdx.x * XBLK;

  float4v acc[4][4];
  #pragma unroll
  for (int mi = 0; mi < 4; ++mi)
    #pragma unroll
    for (int ni = 0; ni < 4; ++ni)
      acc[mi][ni] = (float4v){0.f, 0.f, 0.f, 0.f};

  for (int kc = 0; kc < 4; ++kc) {
    __syncthreads();
    {
      const unsigned char* ws_ = wimg + kc * 65536;
      #pragma unroll
      for (int i = 0; i < 16; ++i)
        lds_load16(ws_ + i * 4096 + tid * 16, lds_w + i * 4096 + (w << 10));
      const unsigned char* xs_ = xsrc + kc * XCHUNK;
      #pragma unroll
      for (int i = 0; i < 4; ++i)
        lds_load16(xs_ + i * 4096 + tid * 16, lds_x + i * 4096 + (w << 10));
    }
    __syncthreads();
    #pragma unroll
    for (int ks = 0; ks < 4; ++ks) {
      const int ko = ks * 32;
      short8v afr[4], bfr[4];
      #pragma unroll
      for (int mi = 0; mi < 4; ++mi) {
        const int e = w * 64 + mi * 16 + lr;
        const unsigned int sw = (unsigned)(e & 7) << 4;
        const unsigned char* base = lds_w + e * 256;
        short4v lo = *(const short4v*)(base + (((unsigned)((ko + 4 * g) * 2)) ^ sw));
        short4v hi = *(const short4v*)(base + (((unsigned)((ko + 16 + 4 * g) * 2)) ^ sw));
        afr[mi] = __builtin_shufflevector(lo, hi, 0, 1, 2, 3, 4, 5, 6, 7);
      }
      #pragma unroll
      for (int ni = 0; ni < 4; ++ni) {
        const int r = ni * 16 + lr;
        const unsigned int sw = (unsigned)(r & 7) << 4;
        const unsigned char* base = lds_x + r * 256;
        short4v lo = *(const short4v*)(base + (((unsigned)((ko + 4 * g) * 2)) ^ sw));
        short4v hi = *(const short4v*)(base + (((unsigned)((ko + 16 + 4 * g) * 2)) ^ sw));
        bfr[ni] = __builtin_shufflevector(lo, hi, 0, 1, 2, 3, 4, 5, 6, 7);
      }
      #pragma unroll
      for (int mi = 0; mi < 4; ++mi)
        #pragma unroll
        for (int ni = 0; ni < 4; ++ni)
          acc[mi][ni] = __builtin_amdgcn_mfma_f32_16x16x32_bf16(afr[mi], bfr[ni], acc[mi][ni], 0, 0, 0);
    }
  }

  #pragma unroll
  for (int ni = 0; ni < 4; ++ni) {
    const int b = b0 + ni * 16 + lr;
    if (b >= B_TOTAL) continue;
    #pragma unroll
    for (int mi = 0; mi < 4; ++mi) {
      const int e = w * 64 + mi * 16 + g * 4;
      #pragma unroll
      for (int q = 0; q < 4; ++q) {
        float v = acc[mi][ni][q];
        out[(size_t)(e + q) * B_TOTAL + b] = v > 0.f ? v : 0.f;
      }
    }
  }
}

// ---------------------------------------------------------------------------
// Fallback (ws tiny): round-1 fused kernel, known-correct.
// ---------------------------------------------------------------------------
__global__ __launch_bounds__(256, 1) void encoder_fused(
    const int* __restrict__ nodes,
    const int* __restrict__ neigh,
    const float* __restrict__ features,
    const float* __restrict__ weight,
    float* __restrict__ out) {
  __shared__ alignas(16) unsigned char lds_cmb[64 * KDIM * 2];
  __shared__ alignas(16) unsigned char lds_w[EDIM * 128 * 2];

  const int tid = threadIdx.x;
  const int l   = tid & 63;
  const int w   = tid >> 6;
  const int b0  = blockIdx.x * 64;

  for (int rr = 0; rr < 16; ++rr) {
    const int r  = w * 16 + rr;
    const int rb = b0 + r;
    unsigned char* rowp = lds_cmb + r * (KDIM * 2);
    const unsigned int sw = (unsigned)(r & 7) << 4;
    if (rb < B_TOTAL) {
      const int node = nodes[rb];
      float4v selfv = *(const float4v*)(features + (size_t)node * FDIM + l * 4);
      float4v accv = {0.f, 0.f, 0.f, 0.f};
      #pragma unroll
      for (int s = 0; s < NSAMP; ++s) {
        const int ni = neigh[rb * NSAMP + s];
        accv += *(const float4v*)(features + (size_t)ni * FDIM + l * 4);
      }
      accv *= 0.0625f;
      *(short4v*)(rowp + (((unsigned)(l * 8)) ^ sw))       = pack4(selfv);
      *(short4v*)(rowp + (((unsigned)(512 + l * 8)) ^ sw)) = pack4(accv);
    } else {
      short4v z = {0, 0, 0, 0};
      *(short4v*)(rowp + (((unsigned)(l * 8)) ^ sw))       = z;
      *(short4v*)(rowp + (((unsigned)(512 + l * 8)) ^ sw)) = z;
    }
  }

  const int lr = l & 15;
  const int g  = l >> 4;
  float4v acc[4][4];
  #pragma unroll
  for (int mi = 0; mi < 4; ++mi)
    #pragma unroll
    for (int ni = 0; ni < 4; ++ni)
      acc[mi][ni] = (float4v){0.f, 0.f, 0.f, 0.f};

  for (int kc = 0; kc < 4; ++kc) {
    __syncthreads();
    const int k0 = kc * 128;
    for (int i = tid; i < EDIM * 32; i += 256) {
      const int e  = i >> 5;
      const int kq = i & 31;
      float4v wv = *(const float4v*)(weight + (size_t)e * KDIM + k0 + kq * 4);
      *(short4v*)(lds_w + e * 256 + (((unsigned)(kq * 8)) ^ ((unsigned)(e & 7) << 4))) = pack4(wv);
    }
    __syncthreads();
    #pragma unroll
    for (int ks = 0; ks < 4; ++ks) {
      const int ko = ks * 32;
      short8v afr[4], bfr[4];
      #pragma unroll
      for (int mi = 0; mi < 4; ++mi) {
        const int e = w * 64 + mi * 16 + lr;
        const unsigned int sw = (unsigned)(e & 7) << 4;
        const unsigned char* base = lds_w + e * 256;
        short4v lo = *(const short4v*)(base + (((unsigned)((ko + 4 * g) * 2)) ^ sw));
        short4v hi = *(const short4v*)(base + (((unsigned)((ko + 16 + 4 * g) * 2)) ^ sw));
        afr[mi] = __builtin_shufflevector(lo, hi, 0, 1, 2, 3, 4, 5, 6, 7);
      }
      #pragma unroll
      for (int ni = 0; ni < 4; ++ni) {
        const int rrow = ni * 16 + lr;
        const unsigned int sw = (unsigned)(rrow & 7) << 4;
        const unsigned char* base = lds_cmb + rrow * (KDIM * 2);
        const int kk = k0 + ko;
        short4v lo = *(const short4v*)(base + (((unsigned)((kk + 4 * g) * 2)) ^ sw));
        short4v hi = *(const short4v*)(base + (((unsigned)((kk + 16 + 4 * g) * 2)) ^ sw));
        bfr[ni] = __builtin_shufflevector(lo, hi, 0, 1, 2, 3, 4, 5, 6, 7);
      }
      #pragma unroll
      for (int mi = 0; mi < 4; ++mi)
        #pragma unroll
        for (int ni = 0; ni < 4; ++ni)
          acc[mi][ni] = __builtin_amdgcn_mfma_f32_16x16x32_bf16(afr[mi], bfr[ni], acc[mi][ni], 0, 0, 0);
    }
  }

  #pragma unroll
  for (int ni = 0; ni < 4; ++ni) {
    const int b = b0 + ni * 16 + lr;
    if (b >= B_TOTAL) continue;
    #pragma unroll
    for (int mi = 0; mi < 4; ++mi) {
      const int e = w * 64 + mi * 16 + g * 4;
      #pragma unroll
      for (int q = 0; q < 4; ++q) {
        float v = acc[mi][ni][q];
        out[(size_t)(e + q) * B_TOTAL + b] = v > 0.f ? v : 0.f;
      }
    }
  }
}

extern "C" void kernel_launch(void* const* d_in, const int* in_sizes, int n_in,
                              void* d_out, int out_size, void* d_ws, size_t ws_size,
                              hipStream_t stream) {
  const int*   nodes    = (const int*)d_in[0];
  const int*   neigh    = (const int*)d_in[1];
  const float* features = (const float*)d_in[2];
  const float* weight   = (const float*)d_in[3];
  float*       out      = (float*)d_out;

  if (ws_size >= WS_FULL) {
    unsigned char*  ximg = (unsigned char*)d_ws;
    unsigned char*  wimg = (unsigned char*)d_ws + WIMG_OFF;
    unsigned char*  f8   = (unsigned char*)d_ws + F8_OFF;
    unsigned short* fb   = (unsigned short*)((unsigned char*)d_ws + FB_OFF);
    prep_pack<<<FP_BLOCKS + PW_BLOCKS, 256, 0, stream>>>(features, f8, fb, weight, wimg);
    gather_mean_f8b<<<B_PAD / 4, 256, 0, stream>>>(nodes, neigh, fb, f8, ximg);
    gemm_relu<<<NBLK, 256, 0, stream>>>(ximg, wimg, out);
  } else if (ws_size >= WS_F8) {
    unsigned char* ximg = (unsigned char*)d_ws;
    unsigned char* wimg = (unsigned char*)d_ws + WIMG_OFF;
    unsigned char* f8   = (unsigned char*)d_ws + F8_OFF;
    fp8_pack<<<(N_NODES * FDIM / 8 + 255) / 256, 256, 0, stream>>>(features, f8);
    pack_w<<<128, 256, 0, stream>>>(weight, wimg);
    gather_mean_f8<<<B_PAD / 4, 256, 0, stream>>>(nodes, neigh, features, f8, ximg);
    gemm_relu<<<NBLK, 256, 0, stream>>>(ximg, wimg, out);
  } else {
    encoder_fused<<<(B_TOTAL + 63) / 64, 256, 0, stream>>>(nodes, neigh, features, weight, out);
  }
}

// Round 11
// 95.409 us; speedup vs baseline: 1.0228x; 1.0228x over previous
//
#include <hip/hip_runtime.h>

#define N_NODES 100000
#define B_TOTAL 50000
#define NSAMP   16
#define FDIM    256
#define KDIM    512   // 2*FDIM
#define EDIM    256
#define NBT     64    // batch columns per GEMM block
#define B_PAD   50048 // B_TOTAL rounded to NBT
#define NBLK    (B_PAD / NBT)   // 782

// X image: [blk][kc=8][rloc=64][128B swizzled] -> 64KB per blk, 51.2MB total
#define XCHUNK   8192            // 64 rows * 128B
#define XBLK     (8 * XCHUNK)    // 65536
#define XIMG_SZ  ((size_t)NBLK * XBLK)
// W image: [kc=8][e=256][128B swizzled] -> 256KB, after X image
#define WIMG_OFF XIMG_SZ
#define WIMG_SZ  ((size_t)8 * 32768)
// fp8 feature table after W image: [N_NODES][256] e4m3 = 25.6MB
#define F8_OFF   (WIMG_OFF + WIMG_SZ)
#define F8_SZ    ((size_t)N_NODES * FDIM)
#define WS_MAIN  (F8_OFF + F8_SZ)    // ~77.1MB

#define FP_BLOCKS 12500   // N_NODES*FDIM/8/256
#define PW_BLOCKS 128

typedef __attribute__((ext_vector_type(4))) float float4v;
typedef __attribute__((ext_vector_type(2))) float float2v;
typedef __attribute__((ext_vector_type(4))) short short4v;
typedef __attribute__((ext_vector_type(8))) short short8v;
typedef __attribute__((ext_vector_type(2))) unsigned int uint2v;

__device__ __forceinline__ unsigned short f2bf(float f) {
  unsigned int u = __builtin_bit_cast(unsigned int, f);
  u += 0x7FFFu + ((u >> 16) & 1u);   // round-to-nearest-even
  return (unsigned short)(u >> 16);
}

__device__ __forceinline__ short4v pack4(float4v v) {
  short4v r;
  r[0] = (short)f2bf(v[0]);
  r[1] = (short)f2bf(v[1]);
  r[2] = (short)f2bf(v[2]);
  r[3] = (short)f2bf(v[3]);
  return r;
}

// ---------------- fp8 e4m3fn encode/decode (hw builtin if available) -------
#if defined(__has_builtin)
#if __has_builtin(__builtin_amdgcn_cvt_pk_f32_fp8) && __has_builtin(__builtin_amdgcn_cvt_pk_fp8_f32)
#define HAS_HW_FP8 1
#endif
#endif

#ifdef HAS_HW_FP8
__device__ __forceinline__ float2v f8_lo(unsigned int d) {
  return (float2v)__builtin_amdgcn_cvt_pk_f32_fp8((int)d, false);
}
__device__ __forceinline__ float2v f8_hi(unsigned int d) {
  return (float2v)__builtin_amdgcn_cvt_pk_f32_fp8((int)d, true);
}
__device__ __forceinline__ uint2v f8_enc8(float4v a, float4v b) {
  int w0 = __builtin_amdgcn_cvt_pk_fp8_f32(a[0], a[1], 0, false);
  w0 = __builtin_amdgcn_cvt_pk_fp8_f32(a[2], a[3], w0, true);
  int w1 = __builtin_amdgcn_cvt_pk_fp8_f32(b[0], b[1], 0, false);
  w1 = __builtin_amdgcn_cvt_pk_fp8_f32(b[2], b[3], w1, true);
  uint2v r; r[0] = (unsigned)w0; r[1] = (unsigned)w1;
  return r;
}
#else
__device__ __forceinline__ float f8_dec1(unsigned int b) {
  unsigned int s = b >> 7, e = (b >> 3) & 15, m = b & 7;
  float fn = __builtin_bit_cast(float, (s << 31) | ((e + 120) << 23) | (m << 20));
  float fs = (float)(int)m * 0.001953125f;       // m * 2^-9
  fs = s ? -fs : fs;
  return e ? fn : fs;
}
__device__ __forceinline__ float2v f8_lo(unsigned int d) {
  float2v r; r[0] = f8_dec1(d & 255u); r[1] = f8_dec1((d >> 8) & 255u); return r;
}
__device__ __forceinline__ float2v f8_hi(unsigned int d) {
  float2v r; r[0] = f8_dec1((d >> 16) & 255u); r[1] = f8_dec1(d >> 24); return r;
}
__device__ __forceinline__ unsigned int f8_enc1(float x) {
  unsigned int u = __builtin_bit_cast(unsigned int, x);
  unsigned int s = (u >> 31) << 7;
  float ax = __builtin_fabsf(x);
  if (ax < 0.015625f) {
    unsigned int m = (unsigned int)__builtin_rintf(ax * 512.0f);
    return s | m;
  }
  if (ax > 448.0f) return s | 0x7E;
  unsigned int au = u & 0x7fffffffu;
  unsigned int t = au + 0x7FFFFu + ((au >> 20) & 1u);
  unsigned int E = t >> 23;
  return s | (((E - 120u) & 0xFu) << 3) | ((t >> 20) & 7u);
}
__device__ __forceinline__ uint2v f8_enc8(float4v a, float4v b) {
  uint2v r;
  r[0] = f8_enc1(a[0]) | (f8_enc1(a[1]) << 8) | (f8_enc1(a[2]) << 16) | (f8_enc1(a[3]) << 24);
  r[1] = f8_enc1(b[0]) | (f8_enc1(b[1]) << 8) | (f8_enc1(b[2]) << 16) | (f8_enc1(b[3]) << 24);
  return r;
}
#endif

// Inline-asm loads: compiler cannot serialize these; we wait manually.
__device__ __forceinline__ unsigned int ld4(const void* p) {
  unsigned int r;
  asm volatile("global_load_dword %0, %1, off" : "=v"(r) : "v"(p) : "memory");
  return r;
}
__device__ __forceinline__ float4v ld16f(const void* p) {
  float4v r;
  asm volatile("global_load_dwordx4 %0, %1, off" : "=v"(r) : "v"(p) : "memory");
  return r;
}

__device__ __forceinline__ void lds_load16(const void* g, void* l) {
  __builtin_amdgcn_global_load_lds(
      (const __attribute__((address_space(1))) unsigned int*)g,
      (__attribute__((address_space(3))) unsigned int*)l, 16, 0, 0);
}

// ---------------------------------------------------------------------------
// Kernel A: merged prep. Blocks < FP_BLOCKS: features f32 -> fp8 table
// (102MB R + 25.6MB W, streaming). Remainder: W -> bf16 swizzled image
// [kc=8][e=256][128B].
// ---------------------------------------------------------------------------
__global__ __launch_bounds__(256) void prep_pack(
    const float* __restrict__ f, unsigned char* __restrict__ o8,
    const float* __restrict__ weight, unsigned char* __restrict__ wimg) {
  if (blockIdx.x < FP_BLOCKS) {
    const size_t i = ((size_t)blockIdx.x * 256 + threadIdx.x) * 8;
    float4v a = *(const float4v*)(f + i);
    float4v b = *(const float4v*)(f + i + 4);
    *(uint2v*)(o8 + i) = f8_enc8(a, b);
  } else {
    const int idx = (blockIdx.x - FP_BLOCKS) * 256 + threadIdx.x;  // 32768
    const int e  = idx >> 7;        // 0..255
    const int kq = idx & 127;       // float4 group
    const int k  = kq * 4;          // 0..508
    const int kc = k >> 6;          // chunk of 64 k -> 0..7
    const int kl = k & 63;
    float4v wv = *(const float4v*)(weight + (size_t)e * KDIM + k);
    *(short4v*)(wimg + kc * 32768 + e * 128 +
                (((unsigned)(kl * 2)) ^ ((unsigned)(e & 7) << 4))) = pack4(wv);
  }
}

// ---------------------------------------------------------------------------
// Kernel 1: gather + mean (r9 body, new store layout). Self f32 (full
// precision, un-averaged); neighbors fp8 (error damped 4x by the 1/16 mean).
// One wave per row, 17 asm loads in flight, single vmcnt(0).
// Store: lane l -> chunk l>>4 (self 0-3, mean 4-7), byte (l*8&127)^sw.
// ---------------------------------------------------------------------------
__global__ __launch_bounds__(256, 4) void gather_mean_f8(
    const int* __restrict__ nodes,
    const int* __restrict__ neigh,
    const float* __restrict__ features,
    const unsigned char* __restrict__ f8,
    unsigned char* __restrict__ ximg) {
  const int l = threadIdx.x & 63;
  const int w = threadIdx.x >> 6;
  const int row = __builtin_amdgcn_readfirstlane(blockIdx.x * 4 + w);
  if (row >= B_PAD) return;

  const int blk  = row >> 6;
  const int rloc = row & 63;
  unsigned char* base = ximg + (size_t)blk * XBLK + rloc * 128;
  const unsigned int sw  = (unsigned)(rloc & 7) << 4;
  const unsigned int off = (((unsigned)(l * 8)) & 127u) ^ sw;
  const int cs = l >> 4;   // chunk index within self/mean quadrant

  if (row < B_TOTAL) {
    const int node = nodes[row];
    const int* ni = neigh + row * NSAMP;
    float4v vs = ld16f(features + (size_t)node * FDIM + l * 4);
    const size_t fo = (size_t)l * 4;
    unsigned int d0  = ld4(f8 + (size_t)ni[ 0] * FDIM + fo);
    unsigned int d1  = ld4(f8 + (size_t)ni[ 1] * FDIM + fo);
    unsigned int d2  = ld4(f8 + (size_t)ni[ 2] * FDIM + fo);
    unsigned int d3  = ld4(f8 + (size_t)ni[ 3] * FDIM + fo);
    unsigned int d4  = ld4(f8 + (size_t)ni[ 4] * FDIM + fo);
    unsigned int d5  = ld4(f8 + (size_t)ni[ 5] * FDIM + fo);
    unsigned int d6  = ld4(f8 + (size_t)ni[ 6] * FDIM + fo);
    unsigned int d7  = ld4(f8 + (size_t)ni[ 7] * FDIM + fo);
    unsigned int d8  = ld4(f8 + (size_t)ni[ 8] * FDIM + fo);
    unsigned int d9  = ld4(f8 + (size_t)ni[ 9] * FDIM + fo);
    unsigned int d10 = ld4(f8 + (size_t)ni[10] * FDIM + fo);
    unsigned int d11 = ld4(f8 + (size_t)ni[11] * FDIM + fo);
    unsigned int d12 = ld4(f8 + (size_t)ni[12] * FDIM + fo);
    unsigned int d13 = ld4(f8 + (size_t)ni[13] * FDIM + fo);
    unsigned int d14 = ld4(f8 + (size_t)ni[14] * FDIM + fo);
    unsigned int d15 = ld4(f8 + (size_t)ni[15] * FDIM + fo);
    asm volatile("s_waitcnt vmcnt(0)" ::: "memory");
    __builtin_amdgcn_sched_barrier(0);

    float2v lo0 = f8_lo(d0)  + f8_lo(d1);
    float2v lo1 = f8_lo(d2)  + f8_lo(d3);
    float2v lo2 = f8_lo(d4)  + f8_lo(d5);
    float2v lo3 = f8_lo(d6)  + f8_lo(d7);
    float2v lo4 = f8_lo(d8)  + f8_lo(d9);
    float2v lo5 = f8_lo(d10) + f8_lo(d11);
    float2v lo6 = f8_lo(d12) + f8_lo(d13);
    float2v lo7 = f8_lo(d14) + f8_lo(d15);
    lo0 += lo1; lo2 += lo3; lo4 += lo5; lo6 += lo7;
    lo0 += lo2; lo4 += lo6;
    lo0 += lo4;
    float2v hi0 = f8_hi(d0)  + f8_hi(d1);
    float2v hi1 = f8_hi(d2)  + f8_hi(d3);
    float2v hi2 = f8_hi(d4)  + f8_hi(d5);
    float2v hi3 = f8_hi(d6)  + f8_hi(d7);
    float2v hi4 = f8_hi(d8)  + f8_hi(d9);
    float2v hi5 = f8_hi(d10) + f8_hi(d11);
    float2v hi6 = f8_hi(d12) + f8_hi(d13);
    float2v hi7 = f8_hi(d14) + f8_hi(d15);
    hi0 += hi1; hi2 += hi3; hi4 += hi5; hi6 += hi7;
    hi0 += hi2; hi4 += hi6;
    hi0 += hi4;

    float4v a0;
    a0[0] = lo0[0] * 0.0625f;
    a0[1] = lo0[1] * 0.0625f;
    a0[2] = hi0[0] * 0.0625f;
    a0[3] = hi0[1] * 0.0625f;

    *(short4v*)(base + cs * XCHUNK + off)       = pack4(vs);   // self: chunks 0-3
    *(short4v*)(base + (4 + cs) * XCHUNK + off) = pack4(a0);   // mean: chunks 4-7
  } else {
    short4v z = {0, 0, 0, 0};
    *(short4v*)(base + cs * XCHUNK + off)       = z;
    *(short4v*)(base + (4 + cs) * XCHUNK + off) = z;
  }
}

// ---------------------------------------------------------------------------
// Kernel 2: out[e,b] = relu( sum_k W[e,k] * X[b,k] ), MFMA bf16.
// K-chunk 64: LDS = 32KB W + 8KB X = 40KB -> 4 blocks/CU -> 1024 slots >=
// 782 tiles -> SINGLE scheduling round (kills the 30% tail of the 80KB
// version). 8 chunks x 2 ks-steps x 16 MFMA.
// ---------------------------------------------------------------------------
__global__ __launch_bounds__(256) void gemm_relu(
    const unsigned char* __restrict__ ximg,
    const unsigned char* __restrict__ wimg,
    float* __restrict__ out) {
  __shared__ alignas(16) unsigned char lds_w[EDIM * 128];   // 32KB
  __shared__ alignas(16) unsigned char lds_x[NBT * 128];    // 8KB

  const int tid = threadIdx.x;
  const int l   = tid & 63;
  const int w   = tid >> 6;
  const int lr  = l & 15;
  const int g   = l >> 4;
  const int b0  = blockIdx.x * NBT;
  const unsigned char* xsrc = ximg + (size_t)blockIdx.x * XBLK;

  float4v acc[4][4];
  #pragma unroll
  for (int mi = 0; mi < 4; ++mi)
    #pragma unroll
    for (int ni = 0; ni < 4; ++ni)
      acc[mi][ni] = (float4v){0.f, 0.f, 0.f, 0.f};

  for (int kc = 0; kc < 8; ++kc) {
    __syncthreads();
    {
      const unsigned char* ws_ = wimg + kc * 32768;
      #pragma unroll
      for (int i = 0; i < 8; ++i)
        lds_load16(ws_ + i * 4096 + tid * 16, lds_w + i * 4096 + (w << 10));
      const unsigned char* xs_ = xsrc + kc * XCHUNK;
      #pragma unroll
      for (int i = 0; i < 2; ++i)
        lds_load16(xs_ + i * 4096 + tid * 16, lds_x + i * 4096 + (w << 10));
    }
    __syncthreads();
    #pragma unroll
    for (int ks = 0; ks < 2; ++ks) {
      const int ko = ks * 32;
      short8v afr[4], bfr[4];
      #pragma unroll
      for (int mi = 0; mi < 4; ++mi) {
        const int e = w * 64 + mi * 16 + lr;
        const unsigned int sw = (unsigned)(e & 7) << 4;
        const unsigned char* base = lds_w + e * 128;
        short4v lo = *(const short4v*)(base + (((unsigned)((ko + 4 * g) * 2)) ^ sw));
        short4v hi = *(const short4v*)(base + (((unsigned)((ko + 16 + 4 * g) * 2)) ^ sw));
        afr[mi] = __builtin_shufflevector(lo, hi, 0, 1, 2, 3, 4, 5, 6, 7);
      }
      #pragma unroll
      for (int ni = 0; ni < 4; ++ni) {
        const int r = ni * 16 + lr;
        const unsigned int sw = (unsigned)(r & 7) << 4;
        const unsigned char* base = lds_x + r * 128;
        short4v lo = *(const short4v*)(base + (((unsigned)((ko + 4 * g) * 2)) ^ sw));
        short4v hi = *(const short4v*)(base + (((unsigned)((ko + 16 + 4 * g) * 2)) ^ sw));
        bfr[ni] = __builtin_shufflevector(lo, hi, 0, 1, 2, 3, 4, 5, 6, 7);
      }
      #pragma unroll
      for (int mi = 0; mi < 4; ++mi)
        #pragma unroll
        for (int ni = 0; ni < 4; ++ni)
          acc[mi][ni] = __builtin_amdgcn_mfma_f32_16x16x32_bf16(afr[mi], bfr[ni], acc[mi][ni], 0, 0, 0);
    }
  }

  #pragma unroll
  for (int ni = 0; ni < 4; ++ni) {
    const int b = b0 + ni * 16 + lr;
    if (b >= B_TOTAL) continue;
    #pragma unroll
    for (int mi = 0; mi < 4; ++mi) {
      const int e = w * 64 + mi * 16 + g * 4;
      #pragma unroll
      for (int q = 0; q < 4; ++q) {
        float v = acc[mi][ni][q];
        out[(size_t)(e + q) * B_TOTAL + b] = v > 0.f ? v : 0.f;
      }
    }
  }
}

// ---------------------------------------------------------------------------
// Fallback (ws too small): round-1 fused kernel, known-correct.
// ---------------------------------------------------------------------------
__global__ __launch_bounds__(256, 1) void encoder_fused(
    const int* __restrict__ nodes,
    const int* __restrict__ neigh,
    const float* __restrict__ features,
    const float* __restrict__ weight,
    float* __restrict__ out) {
  __shared__ alignas(16) unsigned char lds_cmb[64 * KDIM * 2];
  __shared__ alignas(16) unsigned char lds_w[EDIM * 128 * 2];

  const int tid = threadIdx.x;
  const int l   = tid & 63;
  const int w   = tid >> 6;
  const int b0  = blockIdx.x * 64;

  for (int rr = 0; rr < 16; ++rr) {
    const int r  = w * 16 + rr;
    const int rb = b0 + r;
    unsigned char* rowp = lds_cmb + r * (KDIM * 2);
    const unsigned int sw = (unsigned)(r & 7) << 4;
    if (rb < B_TOTAL) {
      const int node = nodes[rb];
      float4v selfv = *(const float4v*)(features + (size_t)node * FDIM + l * 4);
      float4v accv = {0.f, 0.f, 0.f, 0.f};
      #pragma unroll
      for (int s = 0; s < NSAMP; ++s) {
        const int ni = neigh[rb * NSAMP + s];
        accv += *(const float4v*)(features + (size_t)ni * FDIM + l * 4);
      }
      accv *= 0.0625f;
      *(short4v*)(rowp + (((unsigned)(l * 8)) ^ sw))       = pack4(selfv);
      *(short4v*)(rowp + (((unsigned)(512 + l * 8)) ^ sw)) = pack4(accv);
    } else {
      short4v z = {0, 0, 0, 0};
      *(short4v*)(rowp + (((unsigned)(l * 8)) ^ sw))       = z;
      *(short4v*)(rowp + (((unsigned)(512 + l * 8)) ^ sw)) = z;
    }
  }

  const int lr = l & 15;
  const int g  = l >> 4;
  float4v acc[4][4];
  #pragma unroll
  for (int mi = 0; mi < 4; ++mi)
    #pragma unroll
    for (int ni = 0; ni < 4; ++ni)
      acc[mi][ni] = (float4v){0.f, 0.f, 0.f, 0.f};

  for (int kc = 0; kc < 4; ++kc) {
    __syncthreads();
    const int k0 = kc * 128;
    for (int i = tid; i < EDIM * 32; i += 256) {
      const int e  = i >> 5;
      const int kq = i & 31;
      float4v wv = *(const float4v*)(weight + (size_t)e * KDIM + k0 + kq * 4);
      *(short4v*)(lds_w + e * 256 + (((unsigned)(kq * 8)) ^ ((unsigned)(e & 7) << 4))) = pack4(wv);
    }
    __syncthreads();
    #pragma unroll
    for (int ks = 0; ks < 4; ++ks) {
      const int ko = ks * 32;
      short8v afr[4], bfr[4];
      #pragma unroll
      for (int mi = 0; mi < 4; ++mi) {
        const int e = w * 64 + mi * 16 + lr;
        const unsigned int sw = (unsigned)(e & 7) << 4;
        const unsigned char* base = lds_w + e * 256;
        short4v lo = *(const short4v*)(base + (((unsigned)((ko + 4 * g) * 2)) ^ sw));
        short4v hi = *(const short4v*)(base + (((unsigned)((ko + 16 + 4 * g) * 2)) ^ sw));
        afr[mi] = __builtin_shufflevector(lo, hi, 0, 1, 2, 3, 4, 5, 6, 7);
      }
      #pragma unroll
      for (int ni = 0; ni < 4; ++ni) {
        const int rrow = ni * 16 + lr;
        const unsigned int sw = (unsigned)(rrow & 7) << 4;
        const unsigned char* base = lds_cmb + rrow * (KDIM * 2);
        const int kk = k0 + ko;
        short4v lo = *(const short4v*)(base + (((unsigned)((kk + 4 * g) * 2)) ^ sw));
        short4v hi = *(const short4v*)(base + (((unsigned)((kk + 16 + 4 * g) * 2)) ^ sw));
        bfr[ni] = __builtin_shufflevector(lo, hi, 0, 1, 2, 3, 4, 5, 6, 7);
      }
      #pragma unroll
      for (int mi = 0; mi < 4; ++mi)
        #pragma unroll
        for (int ni = 0; ni < 4; ++ni)
          acc[mi][ni] = __builtin_amdgcn_mfma_f32_16x16x32_bf16(afr[mi], bfr[ni], acc[mi][ni], 0, 0, 0);
    }
  }

  #pragma unroll
  for (int ni = 0; ni < 4; ++ni) {
    const int b = b0 + ni * 16 + lr;
    if (b >= B_TOTAL) continue;
    #pragma unroll
    for (int mi = 0; mi < 4; ++mi) {
      const int e = w * 64 + mi * 16 + g * 4;
      #pragma unroll
      for (int q = 0; q < 4; ++q) {
        float v = acc[mi][ni][q];
        out[(size_t)(e + q) * B_TOTAL + b] = v > 0.f ? v : 0.f;
      }
    }
  }
}

extern "C" void kernel_launch(void* const* d_in, const int* in_sizes, int n_in,
                              void* d_out, int out_size, void* d_ws, size_t ws_size,
                              hipStream_t stream) {
  const int*   nodes    = (const int*)d_in[0];
  const int*   neigh    = (const int*)d_in[1];
  const float* features = (const float*)d_in[2];
  const float* weight   = (const float*)d_in[3];
  float*       out      = (float*)d_out;

  if (ws_size >= WS_MAIN) {
    unsigned char* ximg = (unsigned char*)d_ws;
    unsigned char* wimg = (unsigned char*)d_ws + WIMG_OFF;
    unsigned char* f8   = (unsigned char*)d_ws + F8_OFF;
    prep_pack<<<FP_BLOCKS + PW_BLOCKS, 256, 0, stream>>>(features, f8, weight, wimg);
    gather_mean_f8<<<B_PAD / 4, 256, 0, stream>>>(nodes, neigh, features, f8, ximg);
    gemm_relu<<<NBLK, 256, 0, stream>>>(ximg, wimg, out);
  } else {
    encoder_fused<<<(B_TOTAL + 63) / 64, 256, 0, stream>>>(nodes, neigh, features, weight, out);
  }
}

// Round 12
// 91.437 us; speedup vs baseline: 1.0672x; 1.0434x over previous
//
#include <hip/hip_runtime.h>

#define N_NODES 100000
#define B_TOTAL 50000
#define NSAMP   16
#define FDIM    256
#define KDIM    512   // 2*FDIM
#define EDIM    256
#define NBT     64    // batch columns per GEMM block
#define B_PAD   50048 // B_TOTAL rounded to NBT
#define NBLK    (B_PAD / NBT)   // 782

// X image: [blk][kc=4][rloc=64][256B swizzled] -> 64KB per blk, 51.2MB total
#define XCHUNK   16384           // 64 rows * 256B
#define XBLK     (4 * XCHUNK)    // 65536
#define XIMG_SZ  ((size_t)NBLK * XBLK)
// W image: [kc=4][e=256][256B swizzled] -> 256KB, after X image
#define WIMG_OFF XIMG_SZ
#define WIMG_SZ  ((size_t)4 * 65536)
// fp8 feature table after W image: [N_NODES][256] e4m3 = 25.6MB
#define F8_OFF   (WIMG_OFF + WIMG_SZ)
#define F8_SZ    ((size_t)N_NODES * FDIM)
#define WS_MAIN  (F8_OFF + F8_SZ)    // ~77.1MB

#define FP_BLOCKS 12500   // N_NODES*FDIM/8/256
#define PW_BLOCKS 128

typedef __attribute__((ext_vector_type(4))) float float4v;
typedef __attribute__((ext_vector_type(2))) float float2v;
typedef __attribute__((ext_vector_type(4))) short short4v;
typedef __attribute__((ext_vector_type(8))) short short8v;
typedef __attribute__((ext_vector_type(2))) unsigned int uint2v;

__device__ __forceinline__ unsigned short f2bf(float f) {
  unsigned int u = __builtin_bit_cast(unsigned int, f);
  u += 0x7FFFu + ((u >> 16) & 1u);   // round-to-nearest-even
  return (unsigned short)(u >> 16);
}

__device__ __forceinline__ short4v pack4(float4v v) {
  short4v r;
  r[0] = (short)f2bf(v[0]);
  r[1] = (short)f2bf(v[1]);
  r[2] = (short)f2bf(v[2]);
  r[3] = (short)f2bf(v[3]);
  return r;
}

// ---------------- fp8 e4m3fn encode/decode (hw builtin if available) -------
#if defined(__has_builtin)
#if __has_builtin(__builtin_amdgcn_cvt_pk_f32_fp8) && __has_builtin(__builtin_amdgcn_cvt_pk_fp8_f32)
#define HAS_HW_FP8 1
#endif
#endif

#ifdef HAS_HW_FP8
__device__ __forceinline__ float2v f8_lo(unsigned int d) {
  return (float2v)__builtin_amdgcn_cvt_pk_f32_fp8((int)d, false);
}
__device__ __forceinline__ float2v f8_hi(unsigned int d) {
  return (float2v)__builtin_amdgcn_cvt_pk_f32_fp8((int)d, true);
}
__device__ __forceinline__ uint2v f8_enc8(float4v a, float4v b) {
  int w0 = __builtin_amdgcn_cvt_pk_fp8_f32(a[0], a[1], 0, false);
  w0 = __builtin_amdgcn_cvt_pk_fp8_f32(a[2], a[3], w0, true);
  int w1 = __builtin_amdgcn_cvt_pk_fp8_f32(b[0], b[1], 0, false);
  w1 = __builtin_amdgcn_cvt_pk_fp8_f32(b[2], b[3], w1, true);
  uint2v r; r[0] = (unsigned)w0; r[1] = (unsigned)w1;
  return r;
}
#else
__device__ __forceinline__ float f8_dec1(unsigned int b) {
  unsigned int s = b >> 7, e = (b >> 3) & 15, m = b & 7;
  float fn = __builtin_bit_cast(float, (s << 31) | ((e + 120) << 23) | (m << 20));
  float fs = (float)(int)m * 0.001953125f;       // m * 2^-9
  fs = s ? -fs : fs;
  return e ? fn : fs;
}
__device__ __forceinline__ float2v f8_lo(unsigned int d) {
  float2v r; r[0] = f8_dec1(d & 255u); r[1] = f8_dec1((d >> 8) & 255u); return r;
}
__device__ __forceinline__ float2v f8_hi(unsigned int d) {
  float2v r; r[0] = f8_dec1((d >> 16) & 255u); r[1] = f8_dec1(d >> 24); return r;
}
__device__ __forceinline__ unsigned int f8_enc1(float x) {
  unsigned int u = __builtin_bit_cast(unsigned int, x);
  unsigned int s = (u >> 31) << 7;
  float ax = __builtin_fabsf(x);
  if (ax < 0.015625f) {
    unsigned int m = (unsigned int)__builtin_rintf(ax * 512.0f);
    return s | m;
  }
  if (ax > 448.0f) return s | 0x7E;
  unsigned int au = u & 0x7fffffffu;
  unsigned int t = au + 0x7FFFFu + ((au >> 20) & 1u);
  unsigned int E = t >> 23;
  return s | (((E - 120u) & 0xFu) << 3) | ((t >> 20) & 7u);
}
__device__ __forceinline__ uint2v f8_enc8(float4v a, float4v b) {
  uint2v r;
  r[0] = f8_enc1(a[0]) | (f8_enc1(a[1]) << 8) | (f8_enc1(a[2]) << 16) | (f8_enc1(a[3]) << 24);
  r[1] = f8_enc1(b[0]) | (f8_enc1(b[1]) << 8) | (f8_enc1(b[2]) << 16) | (f8_enc1(b[3]) << 24);
  return r;
}
#endif

// Inline-asm loads: compiler cannot serialize these; we wait manually.
__device__ __forceinline__ unsigned int ld4(const void* p) {
  unsigned int r;
  asm volatile("global_load_dword %0, %1, off" : "=v"(r) : "v"(p) : "memory");
  return r;
}
__device__ __forceinline__ float4v ld16f(const void* p) {
  float4v r;
  asm volatile("global_load_dwordx4 %0, %1, off" : "=v"(r) : "v"(p) : "memory");
  return r;
}

__device__ __forceinline__ void lds_load16(const void* g, void* l) {
  __builtin_amdgcn_global_load_lds(
      (const __attribute__((address_space(1))) unsigned int*)g,
      (__attribute__((address_space(3))) unsigned int*)l, 16, 0, 0);
}

// ---------------------------------------------------------------------------
// Kernel A: merged prep (one launch). Blocks < FP_BLOCKS: features f32 ->
// fp8 table (102MB R + 25.6MB W streaming). Remainder: W -> bf16 swizzled
// image [kc=4][e=256][256B] (r9 layout).
// ---------------------------------------------------------------------------
__global__ __launch_bounds__(256) void prep_pack(
    const float* __restrict__ f, unsigned char* __restrict__ o8,
    const float* __restrict__ weight, unsigned char* __restrict__ wimg) {
  if (blockIdx.x < FP_BLOCKS) {
    const size_t i = ((size_t)blockIdx.x * 256 + threadIdx.x) * 8;
    float4v a = *(const float4v*)(f + i);
    float4v b = *(const float4v*)(f + i + 4);
    *(uint2v*)(o8 + i) = f8_enc8(a, b);
  } else {
    const int idx = (blockIdx.x - FP_BLOCKS) * 256 + threadIdx.x;  // 32768
    const int e  = idx >> 7;        // 0..255
    const int kq = idx & 127;       // float4 group
    const int k  = kq * 4;
    const int kc = k >> 7;          // chunk of 128 k -> 0..3
    const int kl = k & 127;
    float4v wv = *(const float4v*)(weight + (size_t)e * KDIM + k);
    *(short4v*)(wimg + kc * 65536 + e * 256 +
                (((unsigned)(kl * 2)) ^ ((unsigned)(e & 7) << 4))) = pack4(wv);
  }
}

// ---------------------------------------------------------------------------
// Kernel 1 (r9-proven, byte-identical): gather + mean. Self f32 (full
// precision, un-averaged); neighbors fp8 (error damped 4x by the 1/16 mean).
// One wave per row, 17 asm loads in flight, single vmcnt(0).
// ---------------------------------------------------------------------------
__global__ __launch_bounds__(256, 4) void gather_mean_f8(
    const int* __restrict__ nodes,
    const int* __restrict__ neigh,
    const float* __restrict__ features,
    const unsigned char* __restrict__ f8,
    unsigned char* __restrict__ ximg) {
  const int l = threadIdx.x & 63;
  const int w = threadIdx.x >> 6;
  const int row = __builtin_amdgcn_readfirstlane(blockIdx.x * 4 + w);
  if (row >= B_PAD) return;

  const int blk  = row >> 6;
  const int rloc = row & 63;
  unsigned char* base = ximg + (size_t)blk * XBLK + rloc * 256;
  const unsigned int sw  = (unsigned)(rloc & 7) << 4;
  const unsigned int off = (((unsigned)(l * 8)) & 255u) ^ sw;
  const int kcs = l >> 5;

  if (row < B_TOTAL) {
    const int node = nodes[row];
    const int* ni = neigh + row * NSAMP;
    float4v vs = ld16f(features + (size_t)node * FDIM + l * 4);
    const size_t fo = (size_t)l * 4;
    unsigned int d0  = ld4(f8 + (size_t)ni[ 0] * FDIM + fo);
    unsigned int d1  = ld4(f8 + (size_t)ni[ 1] * FDIM + fo);
    unsigned int d2  = ld4(f8 + (size_t)ni[ 2] * FDIM + fo);
    unsigned int d3  = ld4(f8 + (size_t)ni[ 3] * FDIM + fo);
    unsigned int d4  = ld4(f8 + (size_t)ni[ 4] * FDIM + fo);
    unsigned int d5  = ld4(f8 + (size_t)ni[ 5] * FDIM + fo);
    unsigned int d6  = ld4(f8 + (size_t)ni[ 6] * FDIM + fo);
    unsigned int d7  = ld4(f8 + (size_t)ni[ 7] * FDIM + fo);
    unsigned int d8  = ld4(f8 + (size_t)ni[ 8] * FDIM + fo);
    unsigned int d9  = ld4(f8 + (size_t)ni[ 9] * FDIM + fo);
    unsigned int d10 = ld4(f8 + (size_t)ni[10] * FDIM + fo);
    unsigned int d11 = ld4(f8 + (size_t)ni[11] * FDIM + fo);
    unsigned int d12 = ld4(f8 + (size_t)ni[12] * FDIM + fo);
    unsigned int d13 = ld4(f8 + (size_t)ni[13] * FDIM + fo);
    unsigned int d14 = ld4(f8 + (size_t)ni[14] * FDIM + fo);
    unsigned int d15 = ld4(f8 + (size_t)ni[15] * FDIM + fo);
    asm volatile("s_waitcnt vmcnt(0)" ::: "memory");
    __builtin_amdgcn_sched_barrier(0);

    float2v lo0 = f8_lo(d0)  + f8_lo(d1);
    float2v lo1 = f8_lo(d2)  + f8_lo(d3);
    float2v lo2 = f8_lo(d4)  + f8_lo(d5);
    float2v lo3 = f8_lo(d6)  + f8_lo(d7);
    float2v lo4 = f8_lo(d8)  + f8_lo(d9);
    float2v lo5 = f8_lo(d10) + f8_lo(d11);
    float2v lo6 = f8_lo(d12) + f8_lo(d13);
    float2v lo7 = f8_lo(d14) + f8_lo(d15);
    lo0 += lo1; lo2 += lo3; lo4 += lo5; lo6 += lo7;
    lo0 += lo2; lo4 += lo6;
    lo0 += lo4;
    float2v hi0 = f8_hi(d0)  + f8_hi(d1);
    float2v hi1 = f8_hi(d2)  + f8_hi(d3);
    float2v hi2 = f8_hi(d4)  + f8_hi(d5);
    float2v hi3 = f8_hi(d6)  + f8_hi(d7);
    float2v hi4 = f8_hi(d8)  + f8_hi(d9);
    float2v hi5 = f8_hi(d10) + f8_hi(d11);
    float2v hi6 = f8_hi(d12) + f8_hi(d13);
    float2v hi7 = f8_hi(d14) + f8_hi(d15);
    hi0 += hi1; hi2 += hi3; hi4 += hi5; hi6 += hi7;
    hi0 += hi2; hi4 += hi6;
    hi0 += hi4;

    float4v a0;
    a0[0] = lo0[0] * 0.0625f;
    a0[1] = lo0[1] * 0.0625f;
    a0[2] = hi0[0] * 0.0625f;
    a0[3] = hi0[1] * 0.0625f;

    *(short4v*)(base + kcs * XCHUNK + off)       = pack4(vs);
    *(short4v*)(base + (2 + kcs) * XCHUNK + off) = pack4(a0);
  } else {
    short4v z = {0, 0, 0, 0};
    *(short4v*)(base + kcs * XCHUNK + off)       = z;
    *(short4v*)(base + (2 + kcs) * XCHUNK + off) = z;
  }
}

// ---------------------------------------------------------------------------
// Kernel 2 (r9-proven, byte-identical): out[e,b] = relu(sum_k W[e,k]*X[b,k]).
// K128 chunks, 80KB LDS, 2 blocks/CU.
// ---------------------------------------------------------------------------
__global__ __launch_bounds__(256) void gemm_relu(
    const unsigned char* __restrict__ ximg,
    const unsigned char* __restrict__ wimg,
    float* __restrict__ out) {
  __shared__ alignas(16) unsigned char lds_w[EDIM * 256];   // 64KB
  __shared__ alignas(16) unsigned char lds_x[NBT * 256];    // 16KB

  const int tid = threadIdx.x;
  const int l   = tid & 63;
  const int w   = tid >> 6;
  const int lr  = l & 15;
  const int g   = l >> 4;
  const int b0  = blockIdx.x * NBT;
  const unsigned char* xsrc = ximg + (size_t)blockIdx.x * XBLK;

  float4v acc[4][4];
  #pragma unroll
  for (int mi = 0; mi < 4; ++mi)
    #pragma unroll
    for (int ni = 0; ni < 4; ++ni)
      acc[mi][ni] = (float4v){0.f, 0.f, 0.f, 0.f};

  for (int kc = 0; kc < 4; ++kc) {
    __syncthreads();
    {
      const unsigned char* ws_ = wimg + kc * 65536;
      #pragma unroll
      for (int i = 0; i < 16; ++i)
        lds_load16(ws_ + i * 4096 + tid * 16, lds_w + i * 4096 + (w << 10));
      const unsigned char* xs_ = xsrc + kc * XCHUNK;
      #pragma unroll
      for (int i = 0; i < 4; ++i)
        lds_load16(xs_ + i * 4096 + tid * 16, lds_x + i * 4096 + (w << 10));
    }
    __syncthreads();
    #pragma unroll
    for (int ks = 0; ks < 4; ++ks) {
      const int ko = ks * 32;
      short8v afr[4], bfr[4];
      #pragma unroll
      for (int mi = 0; mi < 4; ++mi) {
        const int e = w * 64 + mi * 16 + lr;
        const unsigned int sw = (unsigned)(e & 7) << 4;
        const unsigned char* base = lds_w + e * 256;
        short4v lo = *(const short4v*)(base + (((unsigned)((ko + 4 * g) * 2)) ^ sw));
        short4v hi = *(const short4v*)(base + (((unsigned)((ko + 16 + 4 * g) * 2)) ^ sw));
        afr[mi] = __builtin_shufflevector(lo, hi, 0, 1, 2, 3, 4, 5, 6, 7);
      }
      #pragma unroll
      for (int ni = 0; ni < 4; ++ni) {
        const int r = ni * 16 + lr;
        const unsigned int sw = (unsigned)(r & 7) << 4;
        const unsigned char* base = lds_x + r * 256;
        short4v lo = *(const short4v*)(base + (((unsigned)((ko + 4 * g) * 2)) ^ sw));
        short4v hi = *(const short4v*)(base + (((unsigned)((ko + 16 + 4 * g) * 2)) ^ sw));
        bfr[ni] = __builtin_shufflevector(lo, hi, 0, 1, 2, 3, 4, 5, 6, 7);
      }
      #pragma unroll
      for (int mi = 0; mi < 4; ++mi)
        #pragma unroll
        for (int ni = 0; ni < 4; ++ni)
          acc[mi][ni] = __builtin_amdgcn_mfma_f32_16x16x32_bf16(afr[mi], bfr[ni], acc[mi][ni], 0, 0, 0);
    }
  }

  #pragma unroll
  for (int ni = 0; ni < 4; ++ni) {
    const int b = b0 + ni * 16 + lr;
    if (b >= B_TOTAL) continue;
    #pragma unroll
    for (int mi = 0; mi < 4; ++mi) {
      const int e = w * 64 + mi * 16 + g * 4;
      #pragma unroll
      for (int q = 0; q < 4; ++q) {
        float v = acc[mi][ni][q];
        out[(size_t)(e + q) * B_TOTAL + b] = v > 0.f ? v : 0.f;
      }
    }
  }
}

// ---------------------------------------------------------------------------
// Fallback (ws too small): round-1 fused kernel, known-correct.
// ---------------------------------------------------------------------------
__global__ __launch_bounds__(256, 1) void encoder_fused(
    const int* __restrict__ nodes,
    const int* __restrict__ neigh,
    const float* __restrict__ features,
    const float* __restrict__ weight,
    float* __restrict__ out) {
  __shared__ alignas(16) unsigned char lds_cmb[64 * KDIM * 2];
  __shared__ alignas(16) unsigned char lds_w[EDIM * 128 * 2];

  const int tid = threadIdx.x;
  const int l   = tid & 63;
  const int w   = tid >> 6;
  const int b0  = blockIdx.x * 64;

  for (int rr = 0; rr < 16; ++rr) {
    const int r  = w * 16 + rr;
    const int rb = b0 + r;
    unsigned char* rowp = lds_cmb + r * (KDIM * 2);
    const unsigned int sw = (unsigned)(r & 7) << 4;
    if (rb < B_TOTAL) {
      const int node = nodes[rb];
      float4v selfv = *(const float4v*)(features + (size_t)node * FDIM + l * 4);
      float4v accv = {0.f, 0.f, 0.f, 0.f};
      #pragma unroll
      for (int s = 0; s < NSAMP; ++s) {
        const int ni = neigh[rb * NSAMP + s];
        accv += *(const float4v*)(features + (size_t)ni * FDIM + l * 4);
      }
      accv *= 0.0625f;
      *(short4v*)(rowp + (((unsigned)(l * 8)) ^ sw))       = pack4(selfv);
      *(short4v*)(rowp + (((unsigned)(512 + l * 8)) ^ sw)) = pack4(accv);
    } else {
      short4v z = {0, 0, 0, 0};
      *(short4v*)(rowp + (((unsigned)(l * 8)) ^ sw))       = z;
      *(short4v*)(rowp + (((unsigned)(512 + l * 8)) ^ sw)) = z;
    }
  }

  const int lr = l & 15;
  const int g  = l >> 4;
  float4v acc[4][4];
  #pragma unroll
  for (int mi = 0; mi < 4; ++mi)
    #pragma unroll
    for (int ni = 0; ni < 4; ++ni)
      acc[mi][ni] = (float4v){0.f, 0.f, 0.f, 0.f};

  for (int kc = 0; kc < 4; ++kc) {
    __syncthreads();
    const int k0 = kc * 128;
    for (int i = tid; i < EDIM * 32; i += 256) {
      const int e  = i >> 5;
      const int kq = i & 31;
      float4v wv = *(const float4v*)(weight + (size_t)e * KDIM + k0 + kq * 4);
      *(short4v*)(lds_w + e * 256 + (((unsigned)(kq * 8)) ^ ((unsigned)(e & 7) << 4))) = pack4(wv);
    }
    __syncthreads();
    #pragma unroll
    for (int ks = 0; ks < 4; ++ks) {
      const int ko = ks * 32;
      short8v afr[4], bfr[4];
      #pragma unroll
      for (int mi = 0; mi < 4; ++mi) {
        const int e = w * 64 + mi * 16 + lr;
        const unsigned int sw = (unsigned)(e & 7) << 4;
        const unsigned char* base = lds_w + e * 256;
        short4v lo = *(const short4v*)(base + (((unsigned)((ko + 4 * g) * 2)) ^ sw));
        short4v hi = *(const short4v*)(base + (((unsigned)((ko + 16 + 4 * g) * 2)) ^ sw));
        afr[mi] = __builtin_shufflevector(lo, hi, 0, 1, 2, 3, 4, 5, 6, 7);
      }
      #pragma unroll
      for (int ni = 0; ni < 4; ++ni) {
        const int rrow = ni * 16 + lr;
        const unsigned int sw = (unsigned)(rrow & 7) << 4;
        const unsigned char* base = lds_cmb + rrow * (KDIM * 2);
        const int kk = k0 + ko;
        short4v lo = *(const short4v*)(base + (((unsigned)((kk + 4 * g) * 2)) ^ sw));
        short4v hi = *(const short4v*)(base + (((unsigned)((kk + 16 + 4 * g) * 2)) ^ sw));
        bfr[ni] = __builtin_shufflevector(lo, hi, 0, 1, 2, 3, 4, 5, 6, 7);
      }
      #pragma unroll
      for (int mi = 0; mi < 4; ++mi)
        #pragma unroll
        for (int ni = 0; ni < 4; ++ni)
          acc[mi][ni] = __builtin_amdgcn_mfma_f32_16x16x32_bf16(afr[mi], bfr[ni], acc[mi][ni], 0, 0, 0);
    }
  }

  #pragma unroll
  for (int ni = 0; ni < 4; ++ni) {
    const int b = b0 + ni * 16 + lr;
    if (b >= B_TOTAL) continue;
    #pragma unroll
    for (int mi = 0; mi < 4; ++mi) {
      const int e = w * 64 + mi * 16 + g * 4;
      #pragma unroll
      for (int q = 0; q < 4; ++q) {
        float v = acc[mi][ni][q];
        out[(size_t)(e + q) * B_TOTAL + b] = v > 0.f ? v : 0.f;
      }
    }
  }
}

extern "C" void kernel_launch(void* const* d_in, const int* in_sizes, int n_in,
                              void* d_out, int out_size, void* d_ws, size_t ws_size,
                              hipStream_t stream) {
  const int*   nodes    = (const int*)d_in[0];
  const int*   neigh    = (const int*)d_in[1];
  const float* features = (const float*)d_in[2];
  const float* weight   = (const float*)d_in[3];
  float*       out      = (float*)d_out;

  if (ws_size >= WS_MAIN) {
    unsigned char* ximg = (unsigned char*)d_ws;
    unsigned char* wimg = (unsigned char*)d_ws + WIMG_OFF;
    unsigned char* f8   = (unsigned char*)d_ws + F8_OFF;
    prep_pack<<<FP_BLOCKS + PW_BLOCKS, 256, 0, stream>>>(features, f8, weight, wimg);
    gather_mean_f8<<<B_PAD / 4, 256, 0, stream>>>(nodes, neigh, features, f8, ximg);
    gemm_relu<<<NBLK, 256, 0, stream>>>(ximg, wimg, out);
  } else {
    encoder_fused<<<(B_TOTAL + 63) / 64, 256, 0, stream>>>(nodes, neigh, features, weight, out);
  }
}